// Round 8
// baseline (93.973 us; speedup 1.0000x reference)
//
#include <hip/hip_runtime.h>

#define BB 4
#define NN 2048
#define DD 256
#define TILE_N 32                 // n per block
#define NPW 8                     // n per wave (4 waves * 8 = 32)
#define NT (NN / TILE_N)          // 64 n-tiles
#define NPAIR (BB * BB)           // 16
#define NBLK (NPAIR * NT)         // 1024 scan blocks
#define WQ_CAP 96                 // per-wave hit queue (lambda ~10.7, 9x headroom)
#define MAXC 64                   // strip-table slots per pair (<=63 cells + end)

// ws layout (bytes): psum 0 (4KB) | pcnt 4096 (4KB) | sstart 8192 (4KB)
//                    sidx 16384 (128KB) | pos2 262144 (256KB)

// Kernel 1: bin each pair's 2048 dst points into 16-px x-strips.
// One block per pair. Output: pos2 (denormed xy, strip-sorted), sidx
// (original m index), sstart (strip prefix offsets, 41 used of 64).
// Rationale (r7 post-mortem): scan is issue-bound on brute-force pair
// tests; strips prune candidates 20x. Exact d2 still decides (binning is
// completeness-only: disc of r=8 spans <=2 strips of width 16).
__global__ __launch_bounds__(256) void bin_kernel(const float* __restrict__ pts_dst,
                                                  const int* __restrict__ hptr,
                                                  const int* __restrict__ wptr,
                                                  float2* __restrict__ pos2,
                                                  unsigned int* __restrict__ sidx,
                                                  unsigned int* __restrict__ sstart) {
    __shared__ unsigned int cnt[MAXC];
    __shared__ unsigned int off[MAXC];
    __shared__ unsigned int cur[MAXC];
    const int pair = blockIdx.x;
    const int tid = threadIdx.x;
    const float sx = ((float)(*wptr) - 1.0f) * 0.5f;
    const float sy = ((float)(*hptr) - 1.0f) * 0.5f;
    const int ncell = min(MAXC - 1, ((*wptr - 1) >> 4) + 1);   // 40 for W=640
    if (tid < MAXC) cnt[tid] = 0u;
    __syncthreads();
    float px[8], py[8];
    int pc[8];
    const float2* src = (const float2*)(pts_dst) + (size_t)pair * NN;
#pragma unroll
    for (int r = 0; r < 8; ++r) {
        const float2 p = src[r * 256 + tid];
        px[r] = fmaf(p.x, sx, sx);                       // denorm: [0, W-1]
        py[r] = fmaf(p.y, sy, sy);
        pc[r] = min(ncell - 1, max(0, (int)(px[r] * 0.0625f)));
        atomicAdd(&cnt[pc[r]], 1u);
    }
    __syncthreads();
    if (tid == 0) {                                      // serial prefix over <=63 cells
        unsigned int run = 0u;
        for (int c = 0; c < ncell; ++c) { off[c] = run; cur[c] = run; run += cnt[c]; }
        for (int c = ncell; c < MAXC; ++c) off[c] = run; // pad: reads past last cell
    }
    __syncthreads();
#pragma unroll
    for (int r = 0; r < 8; ++r) {
        const unsigned int slot = atomicAdd(&cur[pc[r]], 1u);
        pos2[(size_t)pair * NN + slot] = make_float2(px[r], py[r]);
        sidx[(size_t)pair * NN + slot] = (unsigned int)(r * 256 + tid);  // original m
    }
    __syncthreads();
    if (tid < MAXC) sstart[pair * MAXC + tid] = off[tid];
}

// Kernel 2: block = (pair, n-tile of 32). Per n: <=2 strips (~102 contiguous
// candidates) instead of all 2048 m. Exact d2 test -> per-wave LDS queue.
// Tail: 16 hits in parallel (4 lanes/hit), dot + both norms fused.
// No global atomics: partials to private slots.
__global__ __launch_bounds__(256) void scan_kernel(const float* __restrict__ feat,
                                                   const float* __restrict__ pts_src,
                                                   const float2* __restrict__ pos2,
                                                   const unsigned int* __restrict__ sidx,
                                                   const unsigned int* __restrict__ sstart,
                                                   const int* __restrict__ hptr,
                                                   const int* __restrict__ wptr,
                                                   float* __restrict__ psum,
                                                   unsigned int* __restrict__ pcnt) {
    __shared__ unsigned int wq[4][WQ_CAP];
    __shared__ unsigned int wqc[4];
    __shared__ float bsum[4];
    __shared__ unsigned int bcnt[4];
    const int pair = blockIdx.x >> 6;                    // / NT
    const int tile = blockIdx.x & (NT - 1);
    const int i = pair >> 2;
    const int j = pair & 3;
    const float sx = ((float)(*wptr) - 1.0f) * 0.5f;
    const float sy = ((float)(*hptr) - 1.0f) * 0.5f;
    const int ncell = min(MAXC - 1, ((*wptr - 1) >> 4) + 1);

    const int wave = threadIdx.x >> 6;
    const int lane = threadIdx.x & 63;
    if (lane == 0) wqc[wave] = 0u;                       // same-wave order: no barrier

    const int nbase = tile * TILE_N + wave * NPW;
    const float2* ppos = pos2 + (size_t)pair * NN;
    const unsigned int* pidx = sidx + (size_t)pair * NN;

    // per-n setup: denormed src point + candidate range (wave-uniform)
    float psx[NPW], psy[NPW];
    int b0[NPW], e1[NPW];
#pragma unroll
    for (int k = 0; k < NPW; ++k) {
        psx[k] = fmaf(pts_src[(size_t)(i * NN + nbase + k) * 2 + 0], sx, sx);
        psy[k] = fmaf(pts_src[(size_t)(i * NN + nbase + k) * 2 + 1], sy, sy);
        const int c0 = max(0, (int)((psx[k] - 8.0f) * 0.0625f));       // trunc==floor here
        const int c1 = min(ncell - 1, (int)((psx[k] + 8.0f) * 0.0625f));
        b0[k] = (int)sstart[pair * MAXC + c0];
        e1[k] = (int)sstart[pair * MAXC + c1 + 1];       // c1+1 <= ncell <= 63
    }

    // ---- pruned scan: ~2 chunks of 64 candidates per n ----
#pragma unroll 1
    for (int k = 0; k < NPW; ++k) {
        for (int base = b0[k]; base < e1[k]; base += 64) {
            const int t = base + lane;
            const bool in = t < e1[k];
            const float2 p = ppos[in ? t : base];        // safe addr for masked lanes
            const float ax = psx[k] - p.x;
            const float ay = psy[k] - p.y;
            const bool hit = in && (fmaf(ax, ax, ay * ay) <= 64.0f);
            if (__ballot(hit)) {
                if (hit) {
                    const unsigned int slot = atomicAdd(&wqc[wave], 1u);   // LDS
                    if (slot < WQ_CAP)
                        wq[wave][slot] = ((unsigned int)k << 11) | pidx[t];
                }
            }
        }
    }

    // ---- tail: 16 hits at a time, 4 lanes/hit; dot + both norms fused ----
    const unsigned int hc = min(wqc[wave], (unsigned int)WQ_CAP);
    const int g = lane >> 2, sub = lane & 3;
    float lsum = 0.0f;
    for (unsigned int h0 = 0; h0 < hc; h0 += 16) {
        const unsigned int hid = h0 + (unsigned int)g;
        const bool valid = hid < hc;
        float dd = 0.0f, aa = 0.0f, bb = 0.0f;
        if (valid) {
            const unsigned int rec = wq[wave][hid];
            const int m = (int)(rec & 2047u);
            const int n = nbase + (int)(rec >> 11);
            const float4* pa = (const float4*)(feat + (size_t)(j * NN + n) * DD);
            const float4* pb = (const float4*)(feat + (size_t)(i * NN + m) * DD);
#pragma unroll
            for (int t = 0; t < 16; ++t) {
                const float4 a = pa[t * 4 + sub];
                const float4 b = pb[t * 4 + sub];
                dd = fmaf(a.x, b.x, fmaf(a.y, b.y, fmaf(a.z, b.z, fmaf(a.w, b.w, dd))));
                aa = fmaf(a.x, a.x, fmaf(a.y, a.y, fmaf(a.z, a.z, fmaf(a.w, a.w, aa))));
                bb = fmaf(b.x, b.x, fmaf(b.y, b.y, fmaf(b.z, b.z, fmaf(b.w, b.w, bb))));
            }
        }
        dd += __shfl_xor(dd, 1, 64);  aa += __shfl_xor(aa, 1, 64);  bb += __shfl_xor(bb, 1, 64);
        dd += __shfl_xor(dd, 2, 64);  aa += __shfl_xor(aa, 2, 64);  bb += __shfl_xor(bb, 2, 64);
        if (valid && sub == 0) {
            const float p = aa * bb;                     // (|fa|*|fb|)^2 >> eps^2
            float r = rsqrtf(p);
            r = r * (1.5f - 0.5f * p * r * r);           // one Newton step
            lsum += 1.0f - dd * r;
        }
    }
#pragma unroll
    for (int off = 32; off >= 1; off >>= 1) lsum += __shfl_xor(lsum, off, 64);

    // ---- block reduction -> private slot (plain stores, no atomics) ----
    if (lane == 0) { bsum[wave] = lsum; bcnt[wave] = hc; }
    __syncthreads();
    if (threadIdx.x == 0) {
        psum[blockIdx.x] = bsum[0] + bsum[1] + bsum[2] + bsum[3];
        pcnt[blockIdx.x] = bcnt[0] + bcnt[1] + bcnt[2] + bcnt[3];
    }
}

// Kernel 3: reduce the 1024 block partials. One block.
__global__ __launch_bounds__(256) void finalize_kernel(const float* __restrict__ psum,
                                                       const unsigned int* __restrict__ pcnt,
                                                       float* __restrict__ out) {
    float s = 0.0f;
    float c = 0.0f;                                      // hits < 2^24, exact in f32
    for (int t = threadIdx.x; t < NBLK; t += 256) {
        s += psum[t];
        c += (float)pcnt[t];
    }
#pragma unroll
    for (int off = 32; off >= 1; off >>= 1) {
        s += __shfl_xor(s, off, 64);
        c += __shfl_xor(c, off, 64);
    }
    __shared__ float ss[4], cc[4];
    const int wave = threadIdx.x >> 6;
    const int lane = threadIdx.x & 63;
    if (lane == 0) { ss[wave] = s; cc[wave] = c; }
    __syncthreads();
    if (threadIdx.x == 0) {
        const float S = ss[0] + ss[1] + ss[2] + ss[3];
        const float C = cc[0] + cc[1] + cc[2] + cc[3];
        out[0] = S / fmaxf(C, 1.0f);                     // max(cnt, 1)
    }
}

extern "C" void kernel_launch(void* const* d_in, const int* in_sizes, int n_in,
                              void* d_out, int out_size, void* d_ws, size_t ws_size,
                              hipStream_t stream) {
    const float* feat    = (const float*)d_in[0];   // [B,N,D] f32
    const float* pts_src = (const float*)d_in[1];   // [B,N,2] f32
    const float* pts_dst = (const float*)d_in[2];   // [B,B,N,2] f32
    // d_in[3] = invis_idx — unused by the reference
    const int* hptr = (const int*)d_in[4];          // height (scalar)
    const int* wptr = (const int*)d_in[5];          // width  (scalar)
    float* out = (float*)d_out;

    float*        psum   = (float*)d_ws;
    unsigned int* pcnt   = (unsigned int*)((char*)d_ws + 4096);
    unsigned int* sstart = (unsigned int*)((char*)d_ws + 8192);
    unsigned int* sidx   = (unsigned int*)((char*)d_ws + 16384);
    float2*       pos2   = (float2*)((char*)d_ws + 262144);

    bin_kernel<<<NPAIR, 256, 0, stream>>>(pts_dst, hptr, wptr, pos2, sidx, sstart);
    scan_kernel<<<NBLK, 256, 0, stream>>>(feat, pts_src, pos2, sidx, sstart,
                                          hptr, wptr, psum, pcnt);
    finalize_kernel<<<1, 256, 0, stream>>>(psum, pcnt, out);
}

// Round 9
// 87.709 us; speedup vs baseline: 1.0714x; 1.0714x over previous
//
#include <hip/hip_runtime.h>

#define BB 4
#define NN 2048
#define DD 256
#define TILE_N 32                 // n per block
#define NPW 8                     // n per wave (4 waves * 8 = 32)
#define NT (NN / TILE_N)          // 64 n-tiles
#define MSPLIT 2                  // m-range halves
#define MLEN (NN / MSPLIT)        // 1024 m per block
#define MCH (MLEN / 128)          // 8 chunks of 128 m (2 points/lane)
#define WQ_CAP 96                 // per-wave hit queue (lambda ~5.4)
#define NBLK (BB * BB * NT * MSPLIT)   // 2048 blocks = 8/CU, all co-resident

// Best-measured configuration (round 6, 86.2 us) — reverted after r7 (fp16
// features, +1.1) and r8 (spatial binning, +7.8) both regressed vs this.
// Structure: block = (pair, n-tile of 32, m-half of 1024); points read
// directly from global (L2-resident, prefetched 1 chunk ahead, denorm on
// the fly); branch-free min-tree gates a rare slow path that queues hits
// in per-wave LDS; tail processes 16 hits in parallel (4 lanes/hit) with
// dot + both norms fused; partials go to private slots (no global atomics
// — rounds 1-3 measured ~12 ns per serialized same-address atomic).
__global__ __launch_bounds__(256) void scan_kernel(const float* __restrict__ feat,
                                                   const float* __restrict__ pts_src,
                                                   const float* __restrict__ pts_dst,
                                                   const int* __restrict__ hptr,
                                                   const int* __restrict__ wptr,
                                                   float* __restrict__ psum,
                                                   unsigned int* __restrict__ pcnt) {
    __shared__ unsigned int wq[4][WQ_CAP];               // per-wave hit queues
    __shared__ unsigned int wqc[4];
    __shared__ float bsum[4];
    __shared__ unsigned int bcnt[4];
    const int pair  = blockIdx.x >> 7;                   // / (NT*MSPLIT)
    const int tile  = (blockIdx.x >> 1) & (NT - 1);
    const int mhalf = blockIdx.x & 1;
    const int mbase = mhalf * MLEN;
    const int i = pair >> 2;
    const int j = pair & 3;
    const float sx = ((float)(*wptr) - 1.0f) * 0.5f;
    const float sy = ((float)(*hptr) - 1.0f) * 0.5f;

    const int wave = threadIdx.x >> 6;
    const int lane = threadIdx.x & 63;
    if (lane == 0) wqc[wave] = 0u;                       // same-wave order: no barrier

    const int nbase = tile * TILE_N + wave * NPW;
    float psx[NPW], psy[NPW];
#pragma unroll
    for (int k = 0; k < NPW; ++k) {
        psx[k] = fmaf(pts_src[(size_t)(i * NN + nbase + k) * 2 + 0], sx, sx);
        psy[k] = fmaf(pts_src[(size_t)(i * NN + nbase + k) * 2 + 1], sy, sy);
    }

    // lane's view of this block's m-half: float4 = 2 raw points
    const float4* pd = (const float4*)(pts_dst + (size_t)pair * NN * 2 + (size_t)mbase * 2);

    float4 q = pd[lane];                                 // prefetch chunk 0
#pragma unroll
    for (int c = 0; c < MCH; ++c) {
        float4 qn;
        if (c + 1 < MCH) qn = pd[(c + 1) * 64 + lane];   // prefetch next
        const float qx0 = fmaf(q.x, sx, sx), qy0 = fmaf(q.y, sy, sy);
        const float qx1 = fmaf(q.z, sx, sx), qy1 = fmaf(q.w, sy, sy);
        float mn = 1e30f;
#pragma unroll
        for (int k = 0; k < NPW; ++k) {                  // d0/d1 transient (low VGPR)
            const float ax = psx[k] - qx0, ay = psy[k] - qy0;
            const float bx = psx[k] - qx1, by = psy[k] - qy1;
            mn = fminf(mn, fminf(fmaf(ax, ax, ay * ay), fmaf(bx, bx, by * by)));
        }
        if (__ballot(mn <= 64.0f)) {                     // rare slow path: recompute
            const unsigned int m2 = (unsigned int)(mbase + c * 128 + 2 * lane);
#pragma unroll
            for (int k = 0; k < NPW; ++k) {
                const float ax = psx[k] - qx0, ay = psy[k] - qy0;
                const float bx = psx[k] - qx1, by = psy[k] - qy1;
                const float d0 = fmaf(ax, ax, ay * ay);
                const float d1 = fmaf(bx, bx, by * by);
                if (fminf(d0, d1) <= 64.0f) {            // per-k early-out
                    if (d0 <= 64.0f) {
                        const unsigned int slot = atomicAdd(&wqc[wave], 1u);
                        if (slot < WQ_CAP) wq[wave][slot] = ((unsigned int)k << 11) | m2;
                    }
                    if (d1 <= 64.0f) {
                        const unsigned int slot = atomicAdd(&wqc[wave], 1u);
                        if (slot < WQ_CAP) wq[wave][slot] = ((unsigned int)k << 11) | (m2 + 1u);
                    }
                }
            }
        }
        q = qn;
    }

    // ---- tail: 16 hits at a time, 4 lanes/hit; dot + both norms fused ----
    const unsigned int hc = min(wqc[wave], (unsigned int)WQ_CAP);
    const int g = lane >> 2, sub = lane & 3;
    float lsum = 0.0f;
    for (unsigned int h0 = 0; h0 < hc; h0 += 16) {
        const unsigned int hid = h0 + (unsigned int)g;
        const bool valid = hid < hc;
        float dd = 0.0f, aa = 0.0f, bb = 0.0f;
        if (valid) {
            const unsigned int rec = wq[wave][hid];
            const int m = (int)(rec & 2047u);
            const int n = nbase + (int)(rec >> 11);
            const float4* pa = (const float4*)(feat + (size_t)(j * NN + n) * DD);
            const float4* pb = (const float4*)(feat + (size_t)(i * NN + m) * DD);
#pragma unroll
            for (int t = 0; t < 16; ++t) {
                const float4 a = pa[t * 4 + sub];
                const float4 b = pb[t * 4 + sub];
                dd = fmaf(a.x, b.x, fmaf(a.y, b.y, fmaf(a.z, b.z, fmaf(a.w, b.w, dd))));
                aa = fmaf(a.x, a.x, fmaf(a.y, a.y, fmaf(a.z, a.z, fmaf(a.w, a.w, aa))));
                bb = fmaf(b.x, b.x, fmaf(b.y, b.y, fmaf(b.z, b.z, fmaf(b.w, b.w, bb))));
            }
        }
        dd += __shfl_xor(dd, 1, 64);  aa += __shfl_xor(aa, 1, 64);  bb += __shfl_xor(bb, 1, 64);
        dd += __shfl_xor(dd, 2, 64);  aa += __shfl_xor(aa, 2, 64);  bb += __shfl_xor(bb, 2, 64);
        if (valid && sub == 0) {
            const float p = aa * bb;                     // (|fa|*|fb|)^2 >> eps^2
            float r = rsqrtf(p);
            r = r * (1.5f - 0.5f * p * r * r);           // one Newton step
            lsum += 1.0f - dd * r;
        }
    }
#pragma unroll
    for (int off = 32; off >= 1; off >>= 1) lsum += __shfl_xor(lsum, off, 64);

    // ---- block reduction -> private slot (plain stores, no atomics) ----
    if (lane == 0) { bsum[wave] = lsum; bcnt[wave] = hc; }
    __syncthreads();
    if (threadIdx.x == 0) {
        psum[blockIdx.x] = bsum[0] + bsum[1] + bsum[2] + bsum[3];
        pcnt[blockIdx.x] = bcnt[0] + bcnt[1] + bcnt[2] + bcnt[3];
    }
}

// Kernel 2: reduce the 2048 block partials. One block.
__global__ __launch_bounds__(256) void finalize_kernel(const float* __restrict__ psum,
                                                       const unsigned int* __restrict__ pcnt,
                                                       float* __restrict__ out) {
    float s = 0.0f;
    float c = 0.0f;                                      // hits < 2^24, exact in f32
    for (int t = threadIdx.x; t < NBLK; t += 256) {
        s += psum[t];
        c += (float)pcnt[t];
    }
#pragma unroll
    for (int off = 32; off >= 1; off >>= 1) {
        s += __shfl_xor(s, off, 64);
        c += __shfl_xor(c, off, 64);
    }
    __shared__ float ss[4], cc[4];
    const int wave = threadIdx.x >> 6;
    const int lane = threadIdx.x & 63;
    if (lane == 0) { ss[wave] = s; cc[wave] = c; }
    __syncthreads();
    if (threadIdx.x == 0) {
        const float S = ss[0] + ss[1] + ss[2] + ss[3];
        const float C = cc[0] + cc[1] + cc[2] + cc[3];
        out[0] = S / fmaxf(C, 1.0f);                     // max(cnt, 1)
    }
}

extern "C" void kernel_launch(void* const* d_in, const int* in_sizes, int n_in,
                              void* d_out, int out_size, void* d_ws, size_t ws_size,
                              hipStream_t stream) {
    const float* feat    = (const float*)d_in[0];   // [B,N,D] f32
    const float* pts_src = (const float*)d_in[1];   // [B,N,2] f32
    const float* pts_dst = (const float*)d_in[2];   // [B,B,N,2] f32
    // d_in[3] = invis_idx — unused by the reference
    const int* hptr = (const int*)d_in[4];          // height (scalar)
    const int* wptr = (const int*)d_in[5];          // width  (scalar)
    float* out = (float*)d_out;

    float*        psum  = (float*)d_ws;                          // 8 KB
    unsigned int* pcnt  = (unsigned int*)((char*)d_ws + 8192);   // 8 KB

    scan_kernel<<<NBLK, 256, 0, stream>>>(feat, pts_src, pts_dst,
                                          hptr, wptr, psum, pcnt);
    finalize_kernel<<<1, 256, 0, stream>>>(psum, pcnt, out);
}